// Round 13
// baseline (661.265 us; speedup 1.0000x reference)
//
#include <hip/hip_runtime.h>
#include <math.h>
#include <stdint.h>

#define H 256

typedef __attribute__((ext_vector_type(4))) float f32x4;
typedef __attribute__((ext_vector_type(8))) short bf16x8;
typedef __attribute__((ext_vector_type(8))) unsigned short u16x8;

__device__ __forceinline__ float b2f(unsigned short h) { return __uint_as_float(((uint32_t)h) << 16); }
__device__ __forceinline__ unsigned short f2bf(float f) {
    uint32_t u = __float_as_uint(f);
    u = (u + 0x7FFF + ((u >> 16) & 1)) >> 16;   // RNE
    return (unsigned short)u;
}

// async global->LDS, 16B per lane; lds dest must be wave-uniform base + lane*16
__device__ __forceinline__ void gload_lds16(const void* g, void* l) {
    __builtin_amdgcn_global_load_lds(
        (__attribute__((address_space(1))) void*)(uintptr_t)g,
        (__attribute__((address_space(3))) void*)(uint32_t)(uintptr_t)l,
        16, 0, 0);
}

// ---------------- helpers ----------------
__global__ void k_count(const int* __restrict__ ei, int* __restrict__ deg, int E) {
    int e = blockIdx.x * blockDim.x + threadIdx.x;
    if (e < E) atomicAdd(&deg[ei[E + e]], 1);
}

// ---------------- exclusive scan (scan1 also emits dinv) ----------------
#define SCAN_B 512
__global__ void k_scan1(const int* __restrict__ deg, int* __restrict__ row_part,
                        int* __restrict__ bsum, float* __restrict__ dinv, int n) {
    __shared__ int sm[SCAN_B];
    int t = threadIdx.x;
    int i = blockIdx.x * SCAN_B + t;
    int v = (i < n) ? deg[i] : 0;
    if (i < n) dinv[i] = rsqrtf((float)(v + 1));
    sm[t] = v;
    __syncthreads();
    for (int off = 1; off < SCAN_B; off <<= 1) {
        int add = (t >= off) ? sm[t - off] : 0;
        __syncthreads();
        sm[t] += add;
        __syncthreads();
    }
    if (i < n) row_part[i] = sm[t] - v;
    if (t == SCAN_B - 1) bsum[blockIdx.x] = sm[t];
}

__global__ void k_scan2(const int* __restrict__ bsum, int* __restrict__ boff, int nb) {
    __shared__ int sm[1024];
    int t = threadIdx.x;
    int v = (t < nb) ? bsum[t] : 0;
    sm[t] = v;
    __syncthreads();
    for (int off = 1; off < 1024; off <<= 1) {
        int add = (t >= off) ? sm[t - off] : 0;
        __syncthreads();
        sm[t] += add;
        __syncthreads();
    }
    if (t < nb) boff[t] = sm[t] - v;
    if (t == 1023) boff[nb] = sm[t];
}

__global__ void k_scan3(int* __restrict__ row_off, const int* __restrict__ row_part,
                        const int* __restrict__ boff, int n, int nb) {
    int i = blockIdx.x * blockDim.x + threadIdx.x;
    if (i < n) row_off[i] = row_part[i] + boff[i >> 9];
    else if (i == n) row_off[n] = boff[nb];
}

__global__ void k_fill(const int* __restrict__ ei, int* __restrict__ cursor,
                       const int* __restrict__ row_off, int* __restrict__ csr, int E) {
    int e = blockIdx.x * blockDim.x + threadIdx.x;
    if (e >= E) return;
    int src = ei[e];
    int dst = ei[E + e];
    int pos = atomicAdd(&cursor[dst], 1);
    csr[row_off[dst] + pos] = src;
}

// ---------------- W2..W5 -> Wt (transposed, bf16) ----------------
__global__ void k_wprep(const float* __restrict__ Wa, const float* __restrict__ Wb,
                        const float* __restrict__ Wc, const float* __restrict__ Wd,
                        unsigned short* __restrict__ Wt) {
    int idx = blockIdx.x * 256 + threadIdx.x;       // 0 .. 4*65536-1
    int l = idx >> 16, rem = idx & 65535;
    int k = rem >> 8, nn = rem & 255;
    const float* W = (l == 0) ? Wa : (l == 1) ? Wb : (l == 2) ? Wc : Wd;
    Wt[(size_t)l * H * H + nn * H + k] = f2bf(W[rem]);   // Wt[n][k] = W[k][n]
}

// ---------------- aggx: u = dinv .* agg_hat(dinv .* x), x is N x 3 ----------------
__global__ void k_aggx(const float* __restrict__ x, const int* __restrict__ row_off,
                       const int* __restrict__ csr, const float* __restrict__ dinv,
                       float4* __restrict__ u4, int n, int padn) {
    int i = blockIdx.x * blockDim.x + threadIdx.x;
    if (i >= padn) return;
    if (i >= n) { u4[i] = make_float4(0.f, 0.f, 0.f, 0.f); return; }
    float di = dinv[i];
    float a0 = di * x[i * 3 + 0], a1 = di * x[i * 3 + 1], a2 = di * x[i * 3 + 2];
    int ks = row_off[i], ke = row_off[i + 1];
    for (int k = ks; k < ke; k++) {
        int s = csr[k];
        float ds = dinv[s];
        a0 += ds * x[s * 3 + 0];
        a1 += ds * x[s * 3 + 1];
        a2 += ds * x[s * 3 + 2];
    }
    u4[i] = make_float4(a0 * di, a1 * di, a2 * di, 0.f);
}

// ================= shared GEMM body (A-tile in LDS [chunk][row][8], 32KB) =================
// Epilogue reuses the SAME 32KB buffer (stride 256 ushorts) — A-frags are in regs by then.
__device__ __forceinline__ void gemm_body(char* smem, const unsigned short* __restrict__ Wt,
                                          const float* __restrict__ dinv,
                                          unsigned short* __restrict__ out,
                                          int row0, int n, int tid) {
    const int lane = tid & 63;
    const int w = tid >> 6;
    const int g = lane >> 4, r15 = lane & 15;

    // preload all A-frags for the 64-row tile (A-buf dead afterwards)
    bf16x8 af[4][8];
#pragma unroll
    for (int m = 0; m < 4; m++)
#pragma unroll
        for (int t = 0; t < 8; t++)
            af[m][t] = *(const bf16x8*)(smem + ((t * 4 + g) * 64 + m * 16 + r15) * 16);

    float dv[16];
#pragma unroll
    for (int m = 0; m < 4; m++)
#pragma unroll
        for (int j = 0; j < 4; j++) {
            int grow = row0 + m * 16 + g * 4 + j;
            dv[m * 4 + j] = (grow < n) ? dinv[grow] : 0.f;
        }
    __syncthreads();    // everyone done reading A-buf -> reuse as epilogue buffer

    unsigned short* ep = (unsigned short*)smem;
#pragma unroll 2
    for (int s = 0; s < 4; s++) {           // wave w covers cols w*64 + s*16 + r15
        int col = w * 64 + s * 16 + r15;
        f32x4 acc[4] = {};
#pragma unroll
        for (int t = 0; t < 8; t++) {
            bf16x8 wf = *(const bf16x8*)(Wt + (size_t)col * H + t * 32 + g * 8);
#pragma unroll
            for (int m = 0; m < 4; m++)
                acc[m] = __builtin_amdgcn_mfma_f32_16x16x32_bf16(af[m][t], wf, acc[m], 0, 0, 0);
        }
#pragma unroll
        for (int m = 0; m < 4; m++)
#pragma unroll
            for (int j = 0; j < 4; j++) {
                int row = m * 16 + g * 4 + j;
                ep[row * H + col] = f2bf(acc[m][j] * dv[m * 4 + j]);
            }
    }
    __syncthreads();

    // flush: 8 x (256 threads x 16B) -> contiguous 4KB bursts, full-line writes
#pragma unroll
    for (int i = 0; i < 8; i++) {
        int idx = i * 256 + tid;
        int row = idx >> 5, ch = idx & 31;
        u16x8 v = *(const u16x8*)(ep + row * H + ch * 8);
        *(u16x8*)(out + (size_t)(row0 + row) * H + ch * 8) = v;
    }
}

// ---------------- MFMA GEMM: out = bf16((A @ W) * dinv[row]) ----------------
__global__ __launch_bounds__(256, 4)
void k_gemm(const unsigned short* __restrict__ A, const unsigned short* __restrict__ Wt,
            const float* __restrict__ dinv, unsigned short* __restrict__ out, int n) {
    __shared__ char smem[64 * 512];   // 32 KB: A-tile, then epilogue tile
    const int tid = threadIdx.x;
    const int lane = tid & 63;
    const int w = tid >> 6;
    const int row0 = (int)blockIdx.x * 64;

    const unsigned short* src = A + (size_t)(row0 + lane) * H;
#pragma unroll
    for (int q = 0; q < 8; q++) {
        int c = w * 8 + q;
        gload_lds16(src + c * 8, smem + (c * 64 + lane) * 16);
    }
    __syncthreads();
    gemm_body(smem, Wt, dinv, out, row0, n, tid);
}

// ---------------- gemm1: A-tile = bf16(relu(u @ W1 + b1)) built in LDS; then @ W2 ----------------
__global__ __launch_bounds__(256, 4)
void k_gemm1(const float4* __restrict__ u4, const float* __restrict__ W1,
             const float* __restrict__ b1, const unsigned short* __restrict__ Wt,
             const float* __restrict__ dinv, unsigned short* __restrict__ out, int n) {
    __shared__ char smem[64 * 512];   // 32 KB
    const int tid = threadIdx.x;
    const int row0 = (int)blockIdx.x * 64;
    const int row = tid & 63;
    const int cb = tid >> 6;

    float4 u = u4[row0 + row];
#pragma unroll
    for (int c2 = 0; c2 < 8; c2++) {
        int c = cb * 8 + c2;
        int col0 = c * 8;
        bf16x8 hv;
#pragma unroll
        for (int j = 0; j < 8; j++) {
            int col = col0 + j;
            float v = fmaf(u.x, W1[col], fmaf(u.y, W1[256 + col], fmaf(u.z, W1[512 + col], b1[col])));
            hv[j] = (short)f2bf(fmaxf(v, 0.f));
        }
        *(bf16x8*)(smem + (c * 64 + row) * 16) = hv;
    }
    __syncthreads();
    gemm_body(smem, Wt, dinv, out, row0, n, tid);
}

// ---------------- aggregation: one node per half-wave, batched-independent edge loads ----------------
__global__ void k_agg(const unsigned short* __restrict__ hws, const int* __restrict__ row_off,
                      const int* __restrict__ csr, const float* __restrict__ dinv,
                      const float* __restrict__ bias, unsigned short* __restrict__ out, int n) {
    int node = blockIdx.x * 8 + (threadIdx.x >> 5);
    int cl = threadIdx.x & 31;
    if (node >= n) return;

    float acc[8];
    u16x8 sv = *(const u16x8*)(hws + (size_t)node * H + cl * 8);
#pragma unroll
    for (int j = 0; j < 8; j++) acc[j] = b2f(sv[j]);

    int ks = row_off[node], ke = row_off[node + 1];
    for (int k = ks; k < ke; k += 8) {
        int idx[8];
#pragma unroll
        for (int j = 0; j < 8; j++) idx[j] = (k + j < ke) ? csr[k + j] : -1;
        u16x8 v[8];
#pragma unroll
        for (int j = 0; j < 8; j++)
            if (idx[j] >= 0)
                v[j] = *(const u16x8*)(hws + (size_t)idx[j] * H + cl * 8);
#pragma unroll
        for (int j = 0; j < 8; j++)
            if (idx[j] >= 0) {
#pragma unroll
                for (int q = 0; q < 8; q++) acc[q] += b2f(v[j][q]);
            }
    }

    float4 b0 = ((const float4*)bias)[cl * 2];
    float4 b1v = ((const float4*)bias)[cl * 2 + 1];
    float bb[8] = {b0.x, b0.y, b0.z, b0.w, b1v.x, b1v.y, b1v.z, b1v.w};

    float d = dinv[node];
    u16x8 o;
#pragma unroll
    for (int j = 0; j < 8; j++) o[j] = f2bf(fmaxf(fmaf(acc[j], d, bb[j]), 0.f));
    *(u16x8*)(out + (size_t)node * H + cl * 8) = o;
}

// ---------------- mean-pool over sorted batch: column-per-thread ----------------
__global__ void k_pool(const unsigned short* __restrict__ h, const int* __restrict__ batch,
                       float* __restrict__ pooled, float* __restrict__ counts, int n) {
    int nb = gridDim.x;
    int per = (n + nb - 1) / nb;
    int s = blockIdx.x * per;
    int e = min(n, s + per);
    if (s >= e) return;
    int t = threadIdx.x;
    float acc = 0.f;
    float cnt = 0.f;
    int cur = batch[s];
    for (int i = s; i < e; i++) {
        int g = batch[i];
        if (g != cur) {
            atomicAdd(&pooled[cur * H + t], acc);
            if (t == 0) atomicAdd(&counts[cur], cnt);
            acc = 0.f; cnt = 0.f; cur = g;
        }
        acc += b2f(h[(size_t)i * H + t]);
        cnt += 1.f;
    }
    atomicAdd(&pooled[cur * H + t], acc);
    if (t == 0) atomicAdd(&counts[cur], cnt);
}

// ---------------- head ----------------
__global__ void k_out(const float* __restrict__ pooled, const float* __restrict__ counts,
                      const float* __restrict__ Wout, const float* __restrict__ bout,
                      float* __restrict__ out, int G) {
    int t = threadIdx.x;
    if (t >= G * 2) return;
    int g = t >> 1, c = t & 1;
    float s = 0.f;
    for (int k = 0; k < H; k++) s = fmaf(pooled[g * H + k], Wout[k * 2 + c], s);
    float cnt = fmaxf(counts[g], 1.0f);
    float logit = s / cnt + bout[c];
    out[g * 2 + c] = 1.f / (1.f + expf(-logit));
}

// ---------------- launch ----------------
extern "C" void kernel_launch(void* const* d_in, const int* in_sizes, int n_in,
                              void* d_out, int out_size, void* d_ws, size_t ws_size,
                              hipStream_t stream) {
    const float* x    = (const float*)d_in[0];
    const int*   ei   = (const int*)d_in[1];
    const int*   batch= (const int*)d_in[2];
    const float* W1   = (const float*)d_in[3];
    const float* b1   = (const float*)d_in[4];
    const float* Ws[4] = {(const float*)d_in[5], (const float*)d_in[7],
                          (const float*)d_in[9], (const float*)d_in[11]};
    const float* bs[4] = {(const float*)d_in[6], (const float*)d_in[8],
                          (const float*)d_in[10], (const float*)d_in[12]};
    const float* Wout = (const float*)d_in[13];
    const float* bout = (const float*)d_in[14];

    const int N = in_sizes[0] / 3;
    const int E = in_sizes[1] / 2;
    const int G = out_size / 2;
    const int padN = ((N + 127) / 128) * 128;

    char* p = (char*)d_ws;
    auto alloc = [&](size_t bytes) { char* r = p; p += (bytes + 255) & ~(size_t)255; return r; };
    int*    deg      = (int*)alloc((size_t)N * 4);
    int*    cursor   = (int*)alloc((size_t)N * 4);
    float*  counts   = (float*)alloc((size_t)G * 4);
    float*  pooled   = (float*)alloc((size_t)G * H * 4);
    size_t zero_bytes = (size_t)((char*)p - (char*)d_ws);
    float*  dinv     = (float*)alloc((size_t)N * 4);
    int*    row_part = (int*)alloc((size_t)N * 4);
    int*    row_off  = (int*)alloc((size_t)(N + 1) * 4);
    int*    bsum     = (int*)alloc(1024 * 4);
    int*    boff     = (int*)alloc(1025 * 4);
    int*    csr      = (int*)alloc((size_t)E * 4);
    float4* u4       = (float4*)alloc((size_t)padN * 16);
    unsigned short* Wt   = (unsigned short*)alloc((size_t)4 * H * H * 2);
    unsigned short* bufA = (unsigned short*)alloc((size_t)padN * H * 2);
    unsigned short* bufB = (unsigned short*)alloc((size_t)padN * H * 2);

    hipMemsetAsync(d_ws, 0, zero_bytes, stream);
    k_count<<<(E + 255) / 256, 256, 0, stream>>>(ei, deg, E);

    int nb = (N + SCAN_B - 1) / SCAN_B;
    k_scan1<<<nb, SCAN_B, 0, stream>>>(deg, row_part, bsum, dinv, N);
    k_scan2<<<1, 1024, 0, stream>>>(bsum, boff, nb);
    k_scan3<<<(N + 1 + 255) / 256, 256, 0, stream>>>(row_off, row_part, boff, N, nb);
    k_fill<<<(E + 255) / 256, 256, 0, stream>>>(ei, cursor, row_off, csr, E);

    k_wprep<<<4 * H * H / 256, 256, 0, stream>>>(Ws[0], Ws[1], Ws[2], Ws[3], Wt);

    // layer 1+2 head: u = dinv.*agg(dinv.*x);  hws2 = dinv*(relu(u@W1+b1) @ W2)
    k_aggx<<<(padN + 255) / 256, 256, 0, stream>>>(x, row_off, csr, dinv, u4, N, padN);

    const int gemmblk = padN / 64;
    const int aggblk  = (N + 7) / 8;                // 8 half-waves, 1 node each

    k_gemm1<<<gemmblk, 256, 0, stream>>>(u4, W1, b1, Wt, dinv, bufA, N);

    // layers 3..5: agg (h_l) then GEMM (hws_l)
    for (int l = 0; l < 3; l++) {
        k_agg<<<aggblk, 256, 0, stream>>>(bufA, row_off, csr, dinv, bs[l], bufB, N);
        k_gemm<<<gemmblk, 256, 0, stream>>>(bufB, Wt + (size_t)(l + 1) * H * H, dinv, bufA, N);
    }

    // final agg (bias b5) -> h6, then pool
    k_agg<<<aggblk, 256, 0, stream>>>(bufA, row_off, csr, dinv, bs[3], bufB, N);
    k_pool<<<1024, 256, 0, stream>>>(bufB, batch, pooled, counts, N);
    k_out<<<1, 256, 0, stream>>>(pooled, counts, Wout, bout, (float*)d_out, G);
}

// Round 14
// 399.926 us; speedup vs baseline: 1.6535x; 1.6535x over previous
//
#include <hip/hip_runtime.h>
#include <math.h>
#include <stdint.h>

#define H 256
#define EP_STRIDE 264   // ushorts per epilogue row (264*2=528 B, breaks power-of-2 banks)

typedef __attribute__((ext_vector_type(4))) float f32x4;
typedef __attribute__((ext_vector_type(8))) short bf16x8;
typedef __attribute__((ext_vector_type(8))) unsigned short u16x8;

__device__ __forceinline__ float b2f(unsigned short h) { return __uint_as_float(((uint32_t)h) << 16); }
__device__ __forceinline__ unsigned short f2bf(float f) {
    uint32_t u = __float_as_uint(f);
    u = (u + 0x7FFF + ((u >> 16) & 1)) >> 16;   // RNE
    return (unsigned short)u;
}

// async global->LDS, 16B per lane; lds dest must be wave-uniform base + lane*16
__device__ __forceinline__ void gload_lds16(const void* g, void* l) {
    __builtin_amdgcn_global_load_lds(
        (__attribute__((address_space(1))) void*)(uintptr_t)g,
        (__attribute__((address_space(3))) void*)(uint32_t)(uintptr_t)l,
        16, 0, 0);
}

// ---------------- helpers ----------------
__global__ void k_count(const int* __restrict__ ei, int* __restrict__ deg, int E) {
    int e = blockIdx.x * blockDim.x + threadIdx.x;
    if (e < E) atomicAdd(&deg[ei[E + e]], 1);
}

// ---------------- exclusive scan (scan1 also emits dinv) ----------------
#define SCAN_B 512
__global__ void k_scan1(const int* __restrict__ deg, int* __restrict__ row_part,
                        int* __restrict__ bsum, float* __restrict__ dinv, int n) {
    __shared__ int sm[SCAN_B];
    int t = threadIdx.x;
    int i = blockIdx.x * SCAN_B + t;
    int v = (i < n) ? deg[i] : 0;
    if (i < n) dinv[i] = rsqrtf((float)(v + 1));
    sm[t] = v;
    __syncthreads();
    for (int off = 1; off < SCAN_B; off <<= 1) {
        int add = (t >= off) ? sm[t - off] : 0;
        __syncthreads();
        sm[t] += add;
        __syncthreads();
    }
    if (i < n) row_part[i] = sm[t] - v;
    if (t == SCAN_B - 1) bsum[blockIdx.x] = sm[t];
}

__global__ void k_scan2(const int* __restrict__ bsum, int* __restrict__ boff, int nb) {
    __shared__ int sm[1024];
    int t = threadIdx.x;
    int v = (t < nb) ? bsum[t] : 0;
    sm[t] = v;
    __syncthreads();
    for (int off = 1; off < 1024; off <<= 1) {
        int add = (t >= off) ? sm[t - off] : 0;
        __syncthreads();
        sm[t] += add;
        __syncthreads();
    }
    if (t < nb) boff[t] = sm[t] - v;
    if (t == 1023) boff[nb] = sm[t];
}

__global__ void k_scan3(int* __restrict__ row_off, const int* __restrict__ row_part,
                        const int* __restrict__ boff, int n, int nb) {
    int i = blockIdx.x * blockDim.x + threadIdx.x;
    if (i < n) row_off[i] = row_part[i] + boff[i >> 9];
    else if (i == n) row_off[n] = boff[nb];
}

__global__ void k_fill(const int* __restrict__ ei, int* __restrict__ cursor,
                       const int* __restrict__ row_off, int* __restrict__ csr, int E) {
    int e = blockIdx.x * blockDim.x + threadIdx.x;
    if (e >= E) return;
    int src = ei[e];
    int dst = ei[E + e];
    int pos = atomicAdd(&cursor[dst], 1);
    csr[row_off[dst] + pos] = src;
}

// ---------------- W2..W5 -> Wf (MFMA-fragment-major, bf16) ----------------
// Wf[l][((ss*8 + t)*64 + lane)*8 + j] = W[k][c],  k = t*32 + (lane>>4)*8 + j,
// c = ss*16 + (lane&15).  Each wf load in the GEMM is then one contiguous 1KB burst.
__global__ void k_wprep(const float* __restrict__ Wa, const float* __restrict__ Wb,
                        const float* __restrict__ Wc, const float* __restrict__ Wd,
                        unsigned short* __restrict__ Wf) {
    int idx = blockIdx.x * 256 + threadIdx.x;       // 0 .. 4*65536-1
    int l = idx >> 16, rem = idx & 65535;
    int j    = rem & 7;
    int lane = (rem >> 3) & 63;
    int t    = (rem >> 9) & 7;
    int ss   = rem >> 12;
    int g = lane >> 4, r15 = lane & 15;
    int k = t * 32 + g * 8 + j;
    int c = ss * 16 + r15;
    const float* W = (l == 0) ? Wa : (l == 1) ? Wb : (l == 2) ? Wc : Wd;
    Wf[(size_t)l * H * H + rem] = f2bf(W[k * H + c]);
}

// ---------------- aggx: u = dinv .* agg_hat(dinv .* x), x is N x 3 ----------------
__global__ void k_aggx(const float* __restrict__ x, const int* __restrict__ row_off,
                       const int* __restrict__ csr, const float* __restrict__ dinv,
                       float4* __restrict__ u4, int n, int padn) {
    int i = blockIdx.x * blockDim.x + threadIdx.x;
    if (i >= padn) return;
    if (i >= n) { u4[i] = make_float4(0.f, 0.f, 0.f, 0.f); return; }
    float di = dinv[i];
    float a0 = di * x[i * 3 + 0], a1 = di * x[i * 3 + 1], a2 = di * x[i * 3 + 2];
    int ks = row_off[i], ke = row_off[i + 1];
    for (int k = ks; k < ke; k++) {
        int s = csr[k];
        float ds = dinv[s];
        a0 += ds * x[s * 3 + 0];
        a1 += ds * x[s * 3 + 1];
        a2 += ds * x[s * 3 + 2];
    }
    u4[i] = make_float4(a0 * di, a1 * di, a2 * di, 0.f);
}

// ================= shared GEMM body (A-tile in LDS [chunk][row][8]) =================
// Wf is fragment-major: load = wave-uniform base + lane*16 (1KB contiguous burst).
__device__ __forceinline__ void gemm_body(char* smem, const unsigned short* __restrict__ Wf,
                                          const float* __restrict__ dinv,
                                          unsigned short* __restrict__ out,
                                          int row0, int n, int tid) {
    const int lane = tid & 63;
    const int w = tid >> 6;
    const int g = lane >> 4, r15 = lane & 15;

    // preload all A-frags for the 64-row tile (A-buf dead afterwards)
    bf16x8 af[4][8];
#pragma unroll
    for (int m = 0; m < 4; m++)
#pragma unroll
        for (int t = 0; t < 8; t++)
            af[m][t] = *(const bf16x8*)(smem + ((t * 4 + g) * 64 + m * 16 + r15) * 16);

    float dv[16];
#pragma unroll
    for (int m = 0; m < 4; m++)
#pragma unroll
        for (int j = 0; j < 4; j++) {
            int grow = row0 + m * 16 + g * 4 + j;
            dv[m * 4 + j] = (grow < n) ? dinv[grow] : 0.f;
        }
    __syncthreads();    // everyone done reading A-buf -> reuse as epilogue buffer

    const bf16x8* wfrag = (const bf16x8*)Wf;
    unsigned short* ep = (unsigned short*)smem;
#pragma unroll 2
    for (int s = 0; s < 4; s++) {           // wave w covers cols w*64 + s*16 + r15
        int ss = w * 4 + s;                 // global 16-col strip index
        int col = ss * 16 + r15;
        f32x4 acc[4] = {};
#pragma unroll
        for (int t = 0; t < 8; t++) {
            bf16x8 wf = wfrag[(ss * 8 + t) * 64 + lane];   // contiguous 1KB per wave
#pragma unroll
            for (int m = 0; m < 4; m++)
                acc[m] = __builtin_amdgcn_mfma_f32_16x16x32_bf16(af[m][t], wf, acc[m], 0, 0, 0);
        }
#pragma unroll
        for (int m = 0; m < 4; m++)
#pragma unroll
            for (int j = 0; j < 4; j++) {
                int row = m * 16 + g * 4 + j;
                ep[row * EP_STRIDE + col] = f2bf(acc[m][j] * dv[m * 4 + j]);
            }
    }
    __syncthreads();

    // flush: 8 x (256 threads x 16B) -> contiguous 4KB bursts, full-line writes
#pragma unroll
    for (int i = 0; i < 8; i++) {
        int idx = i * 256 + tid;
        int row = idx >> 5, ch = idx & 31;
        u16x8 v = *(const u16x8*)(ep + row * EP_STRIDE + ch * 8);
        *(u16x8*)(out + (size_t)(row0 + row) * H + ch * 8) = v;
    }
}

// ---------------- MFMA GEMM: out = bf16((A @ W) * dinv[row]) ----------------
__global__ __launch_bounds__(256, 2)
void k_gemm(const unsigned short* __restrict__ A, const unsigned short* __restrict__ Wf,
            const float* __restrict__ dinv, unsigned short* __restrict__ out, int n) {
    __shared__ char smem[64 * EP_STRIDE * 2];
    const int tid = threadIdx.x;
    const int lane = tid & 63;
    const int w = tid >> 6;
    const int row0 = (int)blockIdx.x * 64;

    const unsigned short* src = A + (size_t)(row0 + lane) * H;
#pragma unroll
    for (int q = 0; q < 8; q++) {
        int c = w * 8 + q;
        gload_lds16(src + c * 8, smem + (c * 64 + lane) * 16);
    }
    __syncthreads();
    gemm_body(smem, Wf, dinv, out, row0, n, tid);
}

// ---------------- gemm1: A-tile = bf16(relu(u @ W1 + b1)) built in LDS; then @ W2 ----------------
__global__ __launch_bounds__(256, 2)
void k_gemm1(const float4* __restrict__ u4, const float* __restrict__ W1,
             const float* __restrict__ b1, const unsigned short* __restrict__ Wf,
             const float* __restrict__ dinv, unsigned short* __restrict__ out, int n) {
    __shared__ char smem[64 * EP_STRIDE * 2];
    const int tid = threadIdx.x;
    const int row0 = (int)blockIdx.x * 64;
    const int row = tid & 63;
    const int cb = tid >> 6;

    float4 u = u4[row0 + row];
#pragma unroll
    for (int c2 = 0; c2 < 8; c2++) {
        int c = cb * 8 + c2;
        int col0 = c * 8;
        bf16x8 hv;
#pragma unroll
        for (int j = 0; j < 8; j++) {
            int col = col0 + j;
            float v = fmaf(u.x, W1[col], fmaf(u.y, W1[256 + col], fmaf(u.z, W1[512 + col], b1[col])));
            hv[j] = (short)f2bf(fmaxf(v, 0.f));
        }
        *(bf16x8*)(smem + (c * 64 + row) * 16) = hv;
    }
    __syncthreads();
    gemm_body(smem, Wf, dinv, out, row0, n, tid);
}

// ---------------- aggregation: one node per half-wave, batched-independent edge loads ----------------
__global__ void k_agg(const unsigned short* __restrict__ hws, const int* __restrict__ row_off,
                      const int* __restrict__ csr, const float* __restrict__ dinv,
                      const float* __restrict__ bias, unsigned short* __restrict__ out, int n) {
    int node = blockIdx.x * 8 + (threadIdx.x >> 5);
    int cl = threadIdx.x & 31;
    if (node >= n) return;

    float acc[8];
    u16x8 sv = *(const u16x8*)(hws + (size_t)node * H + cl * 8);
#pragma unroll
    for (int j = 0; j < 8; j++) acc[j] = b2f(sv[j]);

    int ks = row_off[node], ke = row_off[node + 1];
    for (int k = ks; k < ke; k += 8) {
        int idx[8];
#pragma unroll
        for (int j = 0; j < 8; j++) idx[j] = (k + j < ke) ? csr[k + j] : -1;
        u16x8 v[8];
#pragma unroll
        for (int j = 0; j < 8; j++)
            if (idx[j] >= 0)
                v[j] = *(const u16x8*)(hws + (size_t)idx[j] * H + cl * 8);
#pragma unroll
        for (int j = 0; j < 8; j++)
            if (idx[j] >= 0) {
#pragma unroll
                for (int q = 0; q < 8; q++) acc[q] += b2f(v[j][q]);
            }
    }

    float4 b0 = ((const float4*)bias)[cl * 2];
    float4 b1v = ((const float4*)bias)[cl * 2 + 1];
    float bb[8] = {b0.x, b0.y, b0.z, b0.w, b1v.x, b1v.y, b1v.z, b1v.w};

    float d = dinv[node];
    u16x8 o;
#pragma unroll
    for (int j = 0; j < 8; j++) o[j] = f2bf(fmaxf(fmaf(acc[j], d, bb[j]), 0.f));
    *(u16x8*)(out + (size_t)node * H + cl * 8) = o;
}

// ---------------- mean-pool over sorted batch: column-per-thread ----------------
__global__ void k_pool(const unsigned short* __restrict__ h, const int* __restrict__ batch,
                       float* __restrict__ pooled, float* __restrict__ counts, int n) {
    int nb = gridDim.x;
    int per = (n + nb - 1) / nb;
    int s = blockIdx.x * per;
    int e = min(n, s + per);
    if (s >= e) return;
    int t = threadIdx.x;
    float acc = 0.f;
    float cnt = 0.f;
    int cur = batch[s];
    for (int i = s; i < e; i++) {
        int g = batch[i];
        if (g != cur) {
            atomicAdd(&pooled[cur * H + t], acc);
            if (t == 0) atomicAdd(&counts[cur], cnt);
            acc = 0.f; cnt = 0.f; cur = g;
        }
        acc += b2f(h[(size_t)i * H + t]);
        cnt += 1.f;
    }
    atomicAdd(&pooled[cur * H + t], acc);
    if (t == 0) atomicAdd(&counts[cur], cnt);
}

// ---------------- head ----------------
__global__ void k_out(const float* __restrict__ pooled, const float* __restrict__ counts,
                      const float* __restrict__ Wout, const float* __restrict__ bout,
                      float* __restrict__ out, int G) {
    int t = threadIdx.x;
    if (t >= G * 2) return;
    int g = t >> 1, c = t & 1;
    float s = 0.f;
    for (int k = 0; k < H; k++) s = fmaf(pooled[g * H + k], Wout[k * 2 + c], s);
    float cnt = fmaxf(counts[g], 1.0f);
    float logit = s / cnt + bout[c];
    out[g * 2 + c] = 1.f / (1.f + expf(-logit));
}

// ---------------- launch ----------------
extern "C" void kernel_launch(void* const* d_in, const int* in_sizes, int n_in,
                              void* d_out, int out_size, void* d_ws, size_t ws_size,
                              hipStream_t stream) {
    const float* x    = (const float*)d_in[0];
    const int*   ei   = (const int*)d_in[1];
    const int*   batch= (const int*)d_in[2];
    const float* W1   = (const float*)d_in[3];
    const float* b1   = (const float*)d_in[4];
    const float* Ws[4] = {(const float*)d_in[5], (const float*)d_in[7],
                          (const float*)d_in[9], (const float*)d_in[11]};
    const float* bs[4] = {(const float*)d_in[6], (const float*)d_in[8],
                          (const float*)d_in[10], (const float*)d_in[12]};
    const float* Wout = (const float*)d_in[13];
    const float* bout = (const float*)d_in[14];

    const int N = in_sizes[0] / 3;
    const int E = in_sizes[1] / 2;
    const int G = out_size / 2;
    const int padN = ((N + 127) / 128) * 128;

    char* p = (char*)d_ws;
    auto alloc = [&](size_t bytes) { char* r = p; p += (bytes + 255) & ~(size_t)255; return r; };
    int*    deg      = (int*)alloc((size_t)N * 4);
    int*    cursor   = (int*)alloc((size_t)N * 4);
    float*  counts   = (float*)alloc((size_t)G * 4);
    float*  pooled   = (float*)alloc((size_t)G * H * 4);
    size_t zero_bytes = (size_t)((char*)p - (char*)d_ws);
    float*  dinv     = (float*)alloc((size_t)N * 4);
    int*    row_part = (int*)alloc((size_t)N * 4);
    int*    row_off  = (int*)alloc((size_t)(N + 1) * 4);
    int*    bsum     = (int*)alloc(1024 * 4);
    int*    boff     = (int*)alloc(1025 * 4);
    int*    csr      = (int*)alloc((size_t)E * 4);
    float4* u4       = (float4*)alloc((size_t)padN * 16);
    unsigned short* Wf   = (unsigned short*)alloc((size_t)4 * H * H * 2);
    unsigned short* bufA = (unsigned short*)alloc((size_t)padN * H * 2);
    unsigned short* bufB = (unsigned short*)alloc((size_t)padN * H * 2);

    hipMemsetAsync(d_ws, 0, zero_bytes, stream);
    k_count<<<(E + 255) / 256, 256, 0, stream>>>(ei, deg, E);

    int nb = (N + SCAN_B - 1) / SCAN_B;
    k_scan1<<<nb, SCAN_B, 0, stream>>>(deg, row_part, bsum, dinv, N);
    k_scan2<<<1, 1024, 0, stream>>>(bsum, boff, nb);
    k_scan3<<<(N + 1 + 255) / 256, 256, 0, stream>>>(row_off, row_part, boff, N, nb);
    k_fill<<<(E + 255) / 256, 256, 0, stream>>>(ei, cursor, row_off, csr, E);

    k_wprep<<<4 * H * H / 256, 256, 0, stream>>>(Ws[0], Ws[1], Ws[2], Ws[3], Wf);

    // layer 1+2 head: u = dinv.*agg(dinv.*x);  hws2 = dinv*(relu(u@W1+b1) @ W2)
    k_aggx<<<(padN + 255) / 256, 256, 0, stream>>>(x, row_off, csr, dinv, u4, N, padN);

    const int gemmblk = padN / 64;
    const int aggblk  = (N + 7) / 8;                // 8 half-waves, 1 node each

    k_gemm1<<<gemmblk, 256, 0, stream>>>(u4, W1, b1, Wf, dinv, bufA, N);

    // layers 3..5: agg (h_l) then GEMM (hws_l)
    for (int l = 0; l < 3; l++) {
        k_agg<<<aggblk, 256, 0, stream>>>(bufA, row_off, csr, dinv, bs[l], bufB, N);
        k_gemm<<<gemmblk, 256, 0, stream>>>(bufB, Wf + (size_t)(l + 1) * H * H, dinv, bufA, N);
    }

    // final agg (bias b5) -> h6, then pool
    k_agg<<<aggblk, 256, 0, stream>>>(bufA, row_off, csr, dinv, bs[3], bufB, N);
    k_pool<<<1024, 256, 0, stream>>>(bufB, batch, pooled, counts, N);
    k_out<<<1, 256, 0, stream>>>(pooled, counts, Wout, bout, (float*)d_out, G);
}